// Round 6
// baseline (229.340 us; speedup 1.0000x reference)
//
#include <hip/hip_runtime.h>
#include <hip/hip_bf16.h>
#include <math.h>

#define M_ROWS 65536
#define NSPLINE 32
#define BM 64            // rows per block
#define WROWS 16         // rows per wave
#define GROUP 4          // splines per iteration
#define NITER (NSPLINE / GROUP)   // 8
#define YS 34            // LDS halfword stride (17*even lane -> 2-way only)
#define WB_ELEMS (32 * 3 * 2 * 64 * 8)   // 98304 fp16

typedef __attribute__((ext_vector_type(8))) _Float16 half8;
typedef __attribute__((ext_vector_type(4))) float floatx4;

// Accurate-enough softplus: log(1+e^t) = t/2 + log(2*cosh(t/2)).
// Even Taylor in u=t^2 through u^4; |err| <= ~5e-6 for |t| <= 1.1.
// Exact log1pf fallback outside (P ~ 1e-7 per eval).  [R5-proven]
__device__ __forceinline__ float softplus_fast(float t) {
    float u = t * t;
    if (u > 1.21f) return log1pf(__expf(t));   // rare, exact
    float p = fmaf(u, -2.6352e-5f, 3.4722222e-4f);
    p = fmaf(u, p, -5.2083333e-3f);
    p = fmaf(u, p, 0.125f);
    p = fmaf(u, p, 0.69314718f);
    return fmaf(t, 0.5f, p);
}

// ---------------------------------------------------------------------------
// Pack W (48x1056 fp32) + bias (1056) into MFMA B-fragment layout, fp16.
// Thread = destination element (gather form, covers ALL of WH -> no memset).
// WH[sp][t][half][lane][j]:
//   k  = half*32 + (lane>>4)*8 + j   (k<48: W[k][col]; k==48: bias; else 0)
//   cl = t*16 + (lane&15), col = sp*33+cl  (cl>=33 -> zero pad)
// ---------------------------------------------------------------------------
__global__ void pack_W(const float* __restrict__ W, const float* __restrict__ b,
                       _Float16* __restrict__ WH) {
    int idx = blockIdx.x * 256 + threadIdx.x;     // < 98304
    int j    = idx & 7;
    int lane = (idx >> 3) & 63;
    int half = (idx >> 9) & 1;
    int tmp  = idx >> 10;
    int t    = tmp % 3;
    int sp   = tmp / 3;
    int k  = half * 32 + ((lane >> 4) << 3) + j;
    int cl = t * 16 + (lane & 15);
    float v = 0.0f;
    if (cl < 33 && k <= 48) {
        int col = sp * 33 + cl;
        v = (k < 48) ? W[k * 1056 + col] : b[col];
    }
    WH[idx] = (_Float16)v;
}

// ---------------------------------------------------------------------------
// Fused: fp16 MFMA GEMM (y = [z2,c,1] @ [W;b]) -> fp16 LDS transpose ->
// spline with R5-proven numerics (softplus_fast, IEEE divides, __expf/__logf).
// 17.4 KB LDS + <=64 VGPR -> 8 blocks/CU (full occupancy).
// ---------------------------------------------------------------------------
__global__ void __launch_bounds__(256, 8) fused_kernel(
    const float* __restrict__ z, const float* __restrict__ c,
    const _Float16* __restrict__ WH, float* __restrict__ out)
{
    __shared__ _Float16 lds_y[4 * 64 * YS];      // 17408 B

    const int tid  = threadIdx.x;
    const int w    = tid >> 6;
    const int lane = tid & 63;
    const int q    = lane >> 4;        // quad 0..3
    const int cc   = lane & 15;
    const int row_base = blockIdx.x * BM + w * WROWS;
    _Float16* lds_wv = lds_y + w * (64 * YS);

    // ---- z2 passthrough: out[:, :32] = z[:, 32:64] for this wave's rows ----
    #pragma unroll
    for (int it = 0; it < 2; ++it) {
        int idx = it * 64 + lane;                 // 0..127 = 16 rows x 8 float4
        int rr  = row_base + (idx >> 3);
        int v4  = idx & 7;
        float4 val = *(const float4*)(z + (size_t)rr * 64 + 32 + v4 * 4);
        *(float4*)(out + (size_t)rr * 64 + v4 * 4) = val;
    }

    // ---- A fragments (fp16, persist): A[m=cc][k], k=(q*8+j) ---------------
    half8 a0, a1;
    {
        const float* zr = z + (size_t)(row_base + cc) * 64 + 32;
        float4 v0 = *(const float4*)(zr + q * 8);
        float4 v1 = *(const float4*)(zr + q * 8 + 4);
        a0[0]=(_Float16)v0.x; a0[1]=(_Float16)v0.y;
        a0[2]=(_Float16)v0.z; a0[3]=(_Float16)v0.w;
        a0[4]=(_Float16)v1.x; a0[5]=(_Float16)v1.y;
        a0[6]=(_Float16)v1.z; a0[7]=(_Float16)v1.w;
        if (q < 2) {
            const float* cr = c + (size_t)(row_base + cc) * 16 + q * 8;
            float4 u0 = *(const float4*)cr;
            float4 u1 = *(const float4*)(cr + 4);
            a1[0]=(_Float16)u0.x; a1[1]=(_Float16)u0.y;
            a1[2]=(_Float16)u0.z; a1[3]=(_Float16)u0.w;
            a1[4]=(_Float16)u1.x; a1[5]=(_Float16)u1.y;
            a1[6]=(_Float16)u1.z; a1[7]=(_Float16)u1.w;
        } else {
            #pragma unroll
            for (int j = 0; j < 8; ++j) a1[j] = (_Float16)0.0f;
            if (q == 2) a1[0] = (_Float16)1.0f;   // k=48 bias row
        }
    }

    float ld_acc = 0.0f;

    #pragma unroll 1
    for (int g = 0; g < NITER; ++g) {
        __syncthreads();   // prior iteration's LDS reads are done

        // ---- GEMM: 4 splines x 3 col-tiles, 2 MFMA each ------------------
        #pragma unroll
        for (int sp = 0; sp < GROUP; ++sp) {
            const int spg = g * GROUP + sp;
            #pragma unroll
            for (int t = 0; t < 3; ++t) {
                const half8* p = (const half8*)WH + (size_t)(spg * 3 + t) * 128 + lane;
                half8 b0 = p[0];
                half8 b1 = p[64];
                floatx4 acc = {0.f, 0.f, 0.f, 0.f};
                acc = __builtin_amdgcn_mfma_f32_16x16x32_f16(a0, b0, acc, 0, 0, 0);
                acc = __builtin_amdgcn_mfma_f32_16x16x32_f16(a1, b1, acc, 0, 0, 0);
                // D layout: row(m) = q*4 + reg, col(n) = cc
                if (t < 2 || cc == 0) {
                    _Float16* dst = lds_wv + (sp * 16 + q * 4) * YS + t * 16 + cc;
                    dst[0]      = (_Float16)acc[0];
                    dst[YS]     = (_Float16)acc[1];
                    dst[2 * YS] = (_Float16)acc[2];
                    dst[3 * YS] = (_Float16)acc[3];
                }
            }
        }
        __syncthreads();

        // ---- spline: task = (row=cc, spline n=g*4+q), all 64 lanes busy --
        const int n = g * GROUP + q;
        const _Float16* my = lds_wv + (q * 16 + cc) * YS;     // = lane*34
        const float in = z[(size_t)(row_base + cc) * 64 + n];

        float wd[16];
        float sew = 0.f;
        #pragma unroll
        for (int i = 0; i < 16; ++i) {
            float e = __expf((float)my[17 + i]);
            wd[i] = e; sew += e;
        }
        const float inv_sew = 0.984f / sew;        // (1 - 16*MIN_BW)/sum
        #pragma unroll
        for (int i = 0; i < 16; ++i) wd[i] = 0.001f + wd[i] * inv_sew;

        float h[17];
        #pragma unroll
        for (int i = 0; i < 17; ++i)
            h[i] = softplus_fast((float)my[i]) + 0.001f;

        float area = 0.f;
        #pragma unroll
        for (int i = 0; i < 16; ++i) area += (h[i] + h[i + 1]) * 0.5f * wd[i];
        const float inv_area = 0.999f / area;      // (1 - MIN_BH)/area
        #pragma unroll
        for (int i = 0; i < 17; ++i) h[i] = 0.001f + h[i] * inv_area;

        float loc = 0.f, cdfl = 0.f;
        float sel_loc = 0.f, sel_w = wd[0], sel_cdf = 0.f;
        float sel_lh = h[0], sel_rh = h[1];
        #pragma unroll
        for (int bn = 1; bn < 16; ++bn) {
            cdfl = fmaf((h[bn - 1] + h[bn]) * 0.5f, wd[bn - 1], cdfl);
            loc += wd[bn - 1];
            if (in >= loc) {                        // monotone: last true wins
                sel_loc = loc; sel_w = wd[bn]; sel_cdf = cdfl;
                sel_lh = h[bn]; sel_rh = h[bn + 1];
            }
        }

        const float alpha = (in - sel_loc) / sel_w;
        const float dh    = sel_rh - sel_lh;
        float o = ((0.5f * dh * sel_w) * alpha + sel_lh * sel_w) * alpha + sel_cdf;
        o = fminf(fmaxf(o, 0.0f), 1.0f);
        out[(size_t)(row_base + cc) * 64 + 32 + n] = o;
        ld_acc += __logf(fmaf(alpha, dh, sel_lh));
    }

    // ---- logdet: lanes {cc, cc+16, cc+32, cc+48} hold row cc's partials ---
    ld_acc += __shfl_down(ld_acc, 32, 64);
    ld_acc += __shfl_down(ld_acc, 16, 64);
    if (q == 0)
        out[(size_t)M_ROWS * 64 + row_base + cc] = ld_acc;
}

extern "C" void kernel_launch(void* const* d_in, const int* in_sizes, int n_in,
                              void* d_out, int out_size, void* d_ws, size_t ws_size,
                              hipStream_t stream) {
    const float* c = (const float*)d_in[0];   // (M, 16)
    const float* z = (const float*)d_in[1];   // (M, 64)
    const float* W = (const float*)d_in[2];   // (48, 1056)
    const float* b = (const float*)d_in[3];   // (1056,)
    float* out = (float*)d_out;               // M*64 (x) then M (logdet)
    _Float16* WH = (_Float16*)d_ws;           // 98304 fp16 = 192 KiB

    pack_W<<<WB_ELEMS / 256, 256, 0, stream>>>(W, b, WH);
    fused_kernel<<<M_ROWS / BM, 256, 0, stream>>>(z, c, WH, out);
}

// Round 7
// 162.339 us; speedup vs baseline: 1.4127x; 1.4127x over previous
//
#include <hip/hip_runtime.h>
#include <hip/hip_bf16.h>
#include <math.h>

#define M_ROWS 65536
#define NSPLINE 32
#define BM 64            // rows per block
#define WROWS 16         // rows per wave
#define GROUP 4          // splines per iteration
#define NITER (NSPLINE / GROUP)   // 8
#define YS 34            // LDS halfword stride (17*even lane -> 2-way only)
#define WB_ELEMS (32 * 3 * 2 * 64 * 8)   // 98304 fp16

typedef __attribute__((ext_vector_type(8))) _Float16 half8;
typedef __attribute__((ext_vector_type(4))) float floatx4;

// Accurate-enough softplus: log(1+e^t) = t/2 + log(2*cosh(t/2)).
// Even Taylor in u=t^2 through u^4; |err| <= ~5e-6 for |t| <= 1.1.
// Exact log1pf fallback outside (P ~ 1e-7 per eval).  [R5-proven]
__device__ __forceinline__ float softplus_fast(float t) {
    float u = t * t;
    if (u > 1.21f) return log1pf(__expf(t));   // rare, exact
    float p = fmaf(u, -2.6352e-5f, 3.4722222e-4f);
    p = fmaf(u, p, -5.2083333e-3f);
    p = fmaf(u, p, 0.125f);
    p = fmaf(u, p, 0.69314718f);
    return fmaf(t, 0.5f, p);
}

// ---------------------------------------------------------------------------
// Pack W (48x1056 fp32) + bias (1056) into MFMA B-fragment layout, fp16.
// Thread = destination element (gather form, covers ALL of WH -> no memset).
// WH[sp][t][half][lane][j]:
//   k  = half*32 + (lane>>4)*8 + j   (k<48: W[k][col]; k==48: bias; else 0)
//   cl = t*16 + (lane&15), col = sp*33+cl  (cl>=33 -> zero pad)
// ---------------------------------------------------------------------------
__global__ void pack_W(const float* __restrict__ W, const float* __restrict__ b,
                       _Float16* __restrict__ WH) {
    int idx = blockIdx.x * 256 + threadIdx.x;     // < 98304
    int j    = idx & 7;
    int lane = (idx >> 3) & 63;
    int half = (idx >> 9) & 1;
    int tmp  = idx >> 10;
    int t    = tmp % 3;
    int sp   = tmp / 3;
    int k  = half * 32 + ((lane >> 4) << 3) + j;
    int cl = t * 16 + (lane & 15);
    float v = 0.0f;
    if (cl < 33 && k <= 48) {
        int col = sp * 33 + cl;
        v = (k < 48) ? W[k * 1056 + col] : b[col];
    }
    WH[idx] = (_Float16)v;
}

// ---------------------------------------------------------------------------
// Fused: fp16 MFMA GEMM (y = [z2,c,1] @ [W;b]) -> fp16 LDS transpose ->
// spline with R5-proven numerics (softplus_fast, IEEE divides, __expf/__logf).
// launch_bounds(256,6): 85-VGPR budget -> NO spills (R6's (256,8)=64-reg cap
// spilled wd[]/h[] to scratch: 330 MB of global spill traffic, 1.6x slower).
// 17.4 KB LDS -> occupancy min(VGPR, LDS, 8-block wave cap) ~ 6-8 blocks/CU.
// ---------------------------------------------------------------------------
__global__ void __launch_bounds__(256, 6) fused_kernel(
    const float* __restrict__ z, const float* __restrict__ c,
    const _Float16* __restrict__ WH, float* __restrict__ out)
{
    __shared__ _Float16 lds_y[4 * 64 * YS];      // 17408 B

    const int tid  = threadIdx.x;
    const int w    = tid >> 6;
    const int lane = tid & 63;
    const int q    = lane >> 4;        // quad 0..3
    const int cc   = lane & 15;
    const int row_base = blockIdx.x * BM + w * WROWS;
    _Float16* lds_wv = lds_y + w * (64 * YS);

    // ---- z2 passthrough: out[:, :32] = z[:, 32:64] for this wave's rows ----
    #pragma unroll
    for (int it = 0; it < 2; ++it) {
        int idx = it * 64 + lane;                 // 0..127 = 16 rows x 8 float4
        int rr  = row_base + (idx >> 3);
        int v4  = idx & 7;
        float4 val = *(const float4*)(z + (size_t)rr * 64 + 32 + v4 * 4);
        *(float4*)(out + (size_t)rr * 64 + v4 * 4) = val;
    }

    // ---- A fragments (fp16, persist): A[m=cc][k], k=(q*8+j) ---------------
    half8 a0, a1;
    {
        const float* zr = z + (size_t)(row_base + cc) * 64 + 32;
        float4 v0 = *(const float4*)(zr + q * 8);
        float4 v1 = *(const float4*)(zr + q * 8 + 4);
        a0[0]=(_Float16)v0.x; a0[1]=(_Float16)v0.y;
        a0[2]=(_Float16)v0.z; a0[3]=(_Float16)v0.w;
        a0[4]=(_Float16)v1.x; a0[5]=(_Float16)v1.y;
        a0[6]=(_Float16)v1.z; a0[7]=(_Float16)v1.w;
        if (q < 2) {
            const float* cr = c + (size_t)(row_base + cc) * 16 + q * 8;
            float4 u0 = *(const float4*)cr;
            float4 u1 = *(const float4*)(cr + 4);
            a1[0]=(_Float16)u0.x; a1[1]=(_Float16)u0.y;
            a1[2]=(_Float16)u0.z; a1[3]=(_Float16)u0.w;
            a1[4]=(_Float16)u1.x; a1[5]=(_Float16)u1.y;
            a1[6]=(_Float16)u1.z; a1[7]=(_Float16)u1.w;
        } else {
            #pragma unroll
            for (int j = 0; j < 8; ++j) a1[j] = (_Float16)0.0f;
            if (q == 2) a1[0] = (_Float16)1.0f;   // k=48 bias row
        }
    }

    float ld_acc = 0.0f;

    #pragma unroll 1
    for (int g = 0; g < NITER; ++g) {
        __syncthreads();   // prior iteration's LDS reads are done

        // ---- GEMM: 4 splines x 3 col-tiles, 2 MFMA each ------------------
        #pragma unroll
        for (int sp = 0; sp < GROUP; ++sp) {
            const int spg = g * GROUP + sp;
            #pragma unroll
            for (int t = 0; t < 3; ++t) {
                const half8* p = (const half8*)WH + (size_t)(spg * 3 + t) * 128 + lane;
                half8 b0 = p[0];
                half8 b1 = p[64];
                floatx4 acc = {0.f, 0.f, 0.f, 0.f};
                acc = __builtin_amdgcn_mfma_f32_16x16x32_f16(a0, b0, acc, 0, 0, 0);
                acc = __builtin_amdgcn_mfma_f32_16x16x32_f16(a1, b1, acc, 0, 0, 0);
                // D layout: row(m) = q*4 + reg, col(n) = cc
                if (t < 2 || cc == 0) {
                    _Float16* dst = lds_wv + (sp * 16 + q * 4) * YS + t * 16 + cc;
                    dst[0]      = (_Float16)acc[0];
                    dst[YS]     = (_Float16)acc[1];
                    dst[2 * YS] = (_Float16)acc[2];
                    dst[3 * YS] = (_Float16)acc[3];
                }
            }
        }
        __syncthreads();

        // ---- spline: task = (row=cc, spline n=g*4+q), all 64 lanes busy --
        const int n = g * GROUP + q;
        const _Float16* my = lds_wv + (q * 16 + cc) * YS;     // = lane*34
        const float in = z[(size_t)(row_base + cc) * 64 + n];

        float wd[16];
        float sew = 0.f;
        #pragma unroll
        for (int i = 0; i < 16; ++i) {
            float e = __expf((float)my[17 + i]);
            wd[i] = e; sew += e;
        }
        const float inv_sew = 0.984f / sew;        // (1 - 16*MIN_BW)/sum
        #pragma unroll
        for (int i = 0; i < 16; ++i) wd[i] = 0.001f + wd[i] * inv_sew;

        float h[17];
        #pragma unroll
        for (int i = 0; i < 17; ++i)
            h[i] = softplus_fast((float)my[i]) + 0.001f;

        float area = 0.f;
        #pragma unroll
        for (int i = 0; i < 16; ++i) area += (h[i] + h[i + 1]) * 0.5f * wd[i];
        const float inv_area = 0.999f / area;      // (1 - MIN_BH)/area
        #pragma unroll
        for (int i = 0; i < 17; ++i) h[i] = 0.001f + h[i] * inv_area;

        float loc = 0.f, cdfl = 0.f;
        float sel_loc = 0.f, sel_w = wd[0], sel_cdf = 0.f;
        float sel_lh = h[0], sel_rh = h[1];
        #pragma unroll
        for (int bn = 1; bn < 16; ++bn) {
            cdfl = fmaf((h[bn - 1] + h[bn]) * 0.5f, wd[bn - 1], cdfl);
            loc += wd[bn - 1];
            if (in >= loc) {                        // monotone: last true wins
                sel_loc = loc; sel_w = wd[bn]; sel_cdf = cdfl;
                sel_lh = h[bn]; sel_rh = h[bn + 1];
            }
        }

        const float alpha = (in - sel_loc) / sel_w;
        const float dh    = sel_rh - sel_lh;
        float o = ((0.5f * dh * sel_w) * alpha + sel_lh * sel_w) * alpha + sel_cdf;
        o = fminf(fmaxf(o, 0.0f), 1.0f);
        out[(size_t)(row_base + cc) * 64 + 32 + n] = o;
        ld_acc += __logf(fmaf(alpha, dh, sel_lh));
    }

    // ---- logdet: lanes {cc, cc+16, cc+32, cc+48} hold row cc's partials ---
    ld_acc += __shfl_down(ld_acc, 32, 64);
    ld_acc += __shfl_down(ld_acc, 16, 64);
    if (q == 0)
        out[(size_t)M_ROWS * 64 + row_base + cc] = ld_acc;
}

extern "C" void kernel_launch(void* const* d_in, const int* in_sizes, int n_in,
                              void* d_out, int out_size, void* d_ws, size_t ws_size,
                              hipStream_t stream) {
    const float* c = (const float*)d_in[0];   // (M, 16)
    const float* z = (const float*)d_in[1];   // (M, 64)
    const float* W = (const float*)d_in[2];   // (48, 1056)
    const float* b = (const float*)d_in[3];   // (1056,)
    float* out = (float*)d_out;               // M*64 (x) then M (logdet)
    _Float16* WH = (_Float16*)d_ws;           // 98304 fp16 = 192 KiB

    pack_W<<<WB_ELEMS / 256, 256, 0, stream>>>(W, b, WH);
    fused_kernel<<<M_ROWS / BM, 256, 0, stream>>>(z, c, WH, out);
}

// Round 8
// 125.238 us; speedup vs baseline: 1.8312x; 1.2962x over previous
//
#include <hip/hip_runtime.h>
#include <hip/hip_bf16.h>
#include <math.h>

#define M_ROWS 65536
#define NSPLINE 32
#define BM 64            // rows per block
#define WROWS 16         // rows per wave
#define GROUP 4          // splines per iteration
#define NITER (NSPLINE / GROUP)   // 8
#define YS 34            // LDS halfword stride (17*even lane -> 2-way only)
#define WB_ELEMS (32 * 3 * 2 * 64 * 8)   // 98304 fp16

typedef __attribute__((ext_vector_type(8))) _Float16 half8;
typedef __attribute__((ext_vector_type(4))) float floatx4;

// Accurate-enough softplus: log(1+e^t) = t/2 + log(2*cosh(t/2)).
// Even Taylor in u=t^2 through u^4; |err| <= ~5e-6 for |t| <= 1.1.
// Exact log1pf fallback outside (P ~ 1e-7 per eval).  [R5-proven]
__device__ __forceinline__ float softplus_fast(float t) {
    float u = t * t;
    if (u > 1.21f) return log1pf(__expf(t));   // rare, exact
    float p = fmaf(u, -2.6352e-5f, 3.4722222e-4f);
    p = fmaf(u, p, -5.2083333e-3f);
    p = fmaf(u, p, 0.125f);
    p = fmaf(u, p, 0.69314718f);
    return fmaf(t, 0.5f, p);
}

// ---------------------------------------------------------------------------
// Pack W (48x1056 fp32) + bias (1056) into MFMA B-fragment layout, fp16.
// Thread = destination element (gather form, covers ALL of WH -> no memset).
// WH[sp][t][half][lane][j]:
//   k  = half*32 + (lane>>4)*8 + j   (k<48: W[k][col]; k==48: bias; else 0)
//   cl = t*16 + (lane&15), col = sp*33+cl  (cl>=33 -> zero pad)
// ---------------------------------------------------------------------------
__global__ void pack_W(const float* __restrict__ W, const float* __restrict__ b,
                       _Float16* __restrict__ WH) {
    int idx = blockIdx.x * 256 + threadIdx.x;     // < 98304
    int j    = idx & 7;
    int lane = (idx >> 3) & 63;
    int half = (idx >> 9) & 1;
    int tmp  = idx >> 10;
    int t    = tmp % 3;
    int sp   = tmp / 3;
    int k  = half * 32 + ((lane >> 4) << 3) + j;
    int cl = t * 16 + (lane & 15);
    float v = 0.0f;
    if (cl < 33 && k <= 48) {
        int col = sp * 33 + cl;
        v = (k < 48) ? W[k * 1056 + col] : b[col];
    }
    WH[idx] = (_Float16)v;
}

// ---------------------------------------------------------------------------
// Fused: fp16 MFMA GEMM (y = [z2,c,1] @ [W;b]) -> fp16 LDS transpose ->
// spline with R5-proven numerics (softplus_fast, IEEE divides, __expf/__logf).
//
// NO waves-per-EU floor: __launch_bounds__ 2nd arg sets amdgpu-waves-per-eu
// MINIMUM, and the allocator then shrinks regs BELOW budget to chase more
// waves, spilling wd[]/h[] to scratch (R6: 32 regs/330MB spill; R7: 40
// regs/110MB). Natural allocation is ~56 regs, spill-free (R5). Occupancy
// then comes from the fp16 LDS footprint: 17.4KB -> up to 9 blocks/CU.
// ---------------------------------------------------------------------------
__global__ void __launch_bounds__(256) fused_kernel(
    const float* __restrict__ z, const float* __restrict__ c,
    const _Float16* __restrict__ WH, float* __restrict__ out)
{
    __shared__ _Float16 lds_y[4 * 64 * YS];      // 17408 B

    const int tid  = threadIdx.x;
    const int w    = tid >> 6;
    const int lane = tid & 63;
    const int q    = lane >> 4;        // quad 0..3
    const int cc   = lane & 15;
    const int row_base = blockIdx.x * BM + w * WROWS;
    _Float16* lds_wv = lds_y + w * (64 * YS);

    // ---- z2 passthrough: out[:, :32] = z[:, 32:64] for this wave's rows ----
    #pragma unroll
    for (int it = 0; it < 2; ++it) {
        int idx = it * 64 + lane;                 // 0..127 = 16 rows x 8 float4
        int rr  = row_base + (idx >> 3);
        int v4  = idx & 7;
        float4 val = *(const float4*)(z + (size_t)rr * 64 + 32 + v4 * 4);
        *(float4*)(out + (size_t)rr * 64 + v4 * 4) = val;
    }

    // ---- A fragments (fp16, persist): A[m=cc][k], k=(q*8+j) ---------------
    half8 a0, a1;
    {
        const float* zr = z + (size_t)(row_base + cc) * 64 + 32;
        float4 v0 = *(const float4*)(zr + q * 8);
        float4 v1 = *(const float4*)(zr + q * 8 + 4);
        a0[0]=(_Float16)v0.x; a0[1]=(_Float16)v0.y;
        a0[2]=(_Float16)v0.z; a0[3]=(_Float16)v0.w;
        a0[4]=(_Float16)v1.x; a0[5]=(_Float16)v1.y;
        a0[6]=(_Float16)v1.z; a0[7]=(_Float16)v1.w;
        if (q < 2) {
            const float* cr = c + (size_t)(row_base + cc) * 16 + q * 8;
            float4 u0 = *(const float4*)cr;
            float4 u1 = *(const float4*)(cr + 4);
            a1[0]=(_Float16)u0.x; a1[1]=(_Float16)u0.y;
            a1[2]=(_Float16)u0.z; a1[3]=(_Float16)u0.w;
            a1[4]=(_Float16)u1.x; a1[5]=(_Float16)u1.y;
            a1[6]=(_Float16)u1.z; a1[7]=(_Float16)u1.w;
        } else {
            #pragma unroll
            for (int j = 0; j < 8; ++j) a1[j] = (_Float16)0.0f;
            if (q == 2) a1[0] = (_Float16)1.0f;   // k=48 bias row
        }
    }

    float ld_acc = 0.0f;

    #pragma unroll 1
    for (int g = 0; g < NITER; ++g) {
        __syncthreads();   // prior iteration's LDS reads are done

        // ---- GEMM: 4 splines x 3 col-tiles, 2 MFMA each ------------------
        #pragma unroll
        for (int sp = 0; sp < GROUP; ++sp) {
            const int spg = g * GROUP + sp;
            #pragma unroll
            for (int t = 0; t < 3; ++t) {
                const half8* p = (const half8*)WH + (size_t)(spg * 3 + t) * 128 + lane;
                half8 b0 = p[0];
                half8 b1 = p[64];
                floatx4 acc = {0.f, 0.f, 0.f, 0.f};
                acc = __builtin_amdgcn_mfma_f32_16x16x32_f16(a0, b0, acc, 0, 0, 0);
                acc = __builtin_amdgcn_mfma_f32_16x16x32_f16(a1, b1, acc, 0, 0, 0);
                // D layout: row(m) = q*4 + reg, col(n) = cc
                if (t < 2 || cc == 0) {
                    _Float16* dst = lds_wv + (sp * 16 + q * 4) * YS + t * 16 + cc;
                    dst[0]      = (_Float16)acc[0];
                    dst[YS]     = (_Float16)acc[1];
                    dst[2 * YS] = (_Float16)acc[2];
                    dst[3 * YS] = (_Float16)acc[3];
                }
            }
        }
        __syncthreads();

        // ---- spline: task = (row=cc, spline n=g*4+q), all 64 lanes busy --
        const int n = g * GROUP + q;
        const _Float16* my = lds_wv + (q * 16 + cc) * YS;     // = lane*34
        const float in = z[(size_t)(row_base + cc) * 64 + n];

        float wd[16];
        float sew = 0.f;
        #pragma unroll
        for (int i = 0; i < 16; ++i) {
            float e = __expf((float)my[17 + i]);
            wd[i] = e; sew += e;
        }
        const float inv_sew = 0.984f / sew;        // (1 - 16*MIN_BW)/sum
        #pragma unroll
        for (int i = 0; i < 16; ++i) wd[i] = 0.001f + wd[i] * inv_sew;

        float h[17];
        #pragma unroll
        for (int i = 0; i < 17; ++i)
            h[i] = softplus_fast((float)my[i]) + 0.001f;

        float area = 0.f;
        #pragma unroll
        for (int i = 0; i < 16; ++i) area += (h[i] + h[i + 1]) * 0.5f * wd[i];
        const float inv_area = 0.999f / area;      // (1 - MIN_BH)/area
        #pragma unroll
        for (int i = 0; i < 17; ++i) h[i] = 0.001f + h[i] * inv_area;

        float loc = 0.f, cdfl = 0.f;
        float sel_loc = 0.f, sel_w = wd[0], sel_cdf = 0.f;
        float sel_lh = h[0], sel_rh = h[1];
        #pragma unroll
        for (int bn = 1; bn < 16; ++bn) {
            cdfl = fmaf((h[bn - 1] + h[bn]) * 0.5f, wd[bn - 1], cdfl);
            loc += wd[bn - 1];
            if (in >= loc) {                        // monotone: last true wins
                sel_loc = loc; sel_w = wd[bn]; sel_cdf = cdfl;
                sel_lh = h[bn]; sel_rh = h[bn + 1];
            }
        }

        const float alpha = (in - sel_loc) / sel_w;
        const float dh    = sel_rh - sel_lh;
        float o = ((0.5f * dh * sel_w) * alpha + sel_lh * sel_w) * alpha + sel_cdf;
        o = fminf(fmaxf(o, 0.0f), 1.0f);
        out[(size_t)(row_base + cc) * 64 + 32 + n] = o;
        ld_acc += __logf(fmaf(alpha, dh, sel_lh));
    }

    // ---- logdet: lanes {cc, cc+16, cc+32, cc+48} hold row cc's partials ---
    ld_acc += __shfl_down(ld_acc, 32, 64);
    ld_acc += __shfl_down(ld_acc, 16, 64);
    if (q == 0)
        out[(size_t)M_ROWS * 64 + row_base + cc] = ld_acc;
}

extern "C" void kernel_launch(void* const* d_in, const int* in_sizes, int n_in,
                              void* d_out, int out_size, void* d_ws, size_t ws_size,
                              hipStream_t stream) {
    const float* c = (const float*)d_in[0];   // (M, 16)
    const float* z = (const float*)d_in[1];   // (M, 64)
    const float* W = (const float*)d_in[2];   // (48, 1056)
    const float* b = (const float*)d_in[3];   // (1056,)
    float* out = (float*)d_out;               // M*64 (x) then M (logdet)
    _Float16* WH = (_Float16*)d_ws;           // 98304 fp16 = 192 KiB

    pack_W<<<WB_ELEMS / 256, 256, 0, stream>>>(W, b, WH);
    fused_kernel<<<M_ROWS / BM, 256, 0, stream>>>(z, c, WH, out);
}